// Round 6
// baseline (77.087 us; speedup 1.0000x reference)
//
#include <hip/hip_runtime.h>
#include <math.h>

#define LFFT 16384
#define MFFT 8192
#define NT   512
#define PITCH 17   // float2 per LDS row (16 + 1 pad)

// Wave-local LDS ordering fence.
#define LDS_FENCE() asm volatile("s_waitcnt lgkmcnt(0)" ::: "memory")

__device__ __forceinline__ float2 cadd(float2 a, float2 b){ return make_float2(a.x+b.x, a.y+b.y); }
__device__ __forceinline__ float2 csub(float2 a, float2 b){ return make_float2(a.x-b.x, a.y-b.y); }
__device__ __forceinline__ float2 cmul(float2 a, float2 b){ return make_float2(a.x*b.x - a.y*b.y, a.x*b.y + a.y*b.x); }
// a * conj(b)
__device__ __forceinline__ float2 cmulc(float2 a, float2 b){ return make_float2(a.x*b.x + a.y*b.y, a.y*b.x - a.x*b.y); }

template<int S> __device__ __forceinline__ float2 mul_is(float2 a) {
    return make_float2(-(float)S * a.y, (float)S * a.x);
}

// Radix-4 butterfly. S=-1 fwd, S=+1 inverse (unnormalized).
template<int S> __device__ __forceinline__ void dft4_t(float2& a0, float2& a1, float2& a2, float2& a3) {
    float2 t0 = cadd(a0, a2);
    float2 t1 = csub(a0, a2);
    float2 t2 = cadd(a1, a3);
    float2 t3 = csub(a1, a3);
    a0 = cadd(t0, t2);
    a2 = csub(t0, t2);
    const float s = (float)S;
    a1 = make_float2(t1.x - s * t3.y, t1.y + s * t3.x);
    a3 = make_float2(t1.x + s * t3.y, t1.y - s * t3.x);
}

#define C16A 0.92387953251128675613f
#define C16B 0.70710678118654752440f
#define C16C 0.38268343236508977173f

// Fully-unrolled 16-point DFT, natural order in and out.
template<int S> __device__ __forceinline__ void dft16_t(float2 r[16]) {
    const float s = (float)S;
    const float2 w1 = make_float2( C16A, s * C16C);
    const float2 w2 = make_float2( C16B, s * C16B);
    const float2 w3 = make_float2( C16C, s * C16A);
    const float2 w6 = make_float2(-C16B, s * C16B);
    const float2 w9 = make_float2(-C16A, -s * C16C);
    float2 g[4][4];
    #pragma unroll
    for (int b = 0; b < 4; ++b) {
        float2 a0 = r[b], a1 = r[b+4], a2 = r[b+8], a3 = r[b+12];
        dft4_t<S>(a0, a1, a2, a3);
        g[b][0] = a0; g[b][1] = a1; g[b][2] = a2; g[b][3] = a3;
    }
    g[1][1] = cmul(g[1][1], w1);  g[1][2] = cmul(g[1][2], w2);  g[1][3] = cmul(g[1][3], w3);
    g[2][1] = cmul(g[2][1], w2);  g[2][2] = mul_is<S>(g[2][2]); g[2][3] = cmul(g[2][3], w6);
    g[3][1] = cmul(g[3][1], w3);  g[3][2] = cmul(g[3][2], w6);  g[3][3] = cmul(g[3][3], w9);
    #pragma unroll
    for (int ka = 0; ka < 4; ++ka) {
        float2 a0 = g[0][ka], a1 = g[1][ka], a2 = g[2][ka], a3 = g[3][ka];
        dft4_t<S>(a0, a1, a2, a3);
        r[ka] = a0; r[ka+4] = a1; r[ka+8] = a2; r[ka+12] = a3;
    }
}

// r[k] *= w^k, k = 1..15
__device__ __forceinline__ void twiddle15(float2 r[16], float2 w) {
    float2 w2 = cmul(w, w);
    float2 we = w2;
    float2 wo = cmul(w, w2);
    r[1] = cmul(r[1], w);
    r[2] = cmul(r[2], we);
    r[3] = cmul(r[3], wo);
    #pragma unroll
    for (int j = 2; j <= 7; ++j) {
        we = cmul(we, w2);  r[2*j]   = cmul(r[2*j],   we);
        wo = cmul(wo, w2);  r[2*j+1] = cmul(r[2*j+1], wo);
    }
}

// ---------------------------------------------------------------------------
// Kernel 1: fp64 evaluation of the S4 generating function K[m] at the L=16384
// roots of unity (natural order), plus the fp32 twiddle table for M=8192.
// ---------------------------------------------------------------------------
__global__ void s4_eval(const float* __restrict__ Lr, const float* __restrict__ Li,
                        const float* __restrict__ Pr, const float* __restrict__ Pi,
                        const float* __restrict__ Br, const float* __restrict__ Bi,
                        const float* __restrict__ Cr, const float* __restrict__ Ci,
                        const float* __restrict__ step_ptr,
                        float2* __restrict__ Kraw, float2* __restrict__ twidM)
{
    int m = blockIdx.x * blockDim.x + threadIdx.x;
    if (m >= LFFT) return;
    if (m < MFFT) {
        double th2 = (-2.0 * M_PI / (double)MFFT) * (double)m;
        double s2, c2;
        sincos(th2, &s2, &c2);
        twidM[m] = make_float2((float)c2, (float)s2);
    }
    double theta = (-2.0 * M_PI / (double)LFFT) * (double)m;
    double si, co;
    sincos(theta, &si, &co);

    double step = (double)step_ptr[0];
    double opr = 1.0 + co, opi = si;   // 1 + Omega
    double omr = 1.0 - co, omi = -si;  // 1 - Omega
    double iden = 1.0 / (opr*opr + opi*opi);
    double gs = 2.0 / step;
    double gr = gs * (omr*opr + omi*opi) * iden;
    double gi = gs * (omi*opr - omr*opi) * iden;
    double cr = 2.0 * opr * iden;
    double ci = -2.0 * opi * iden;

    double k00r=0,k00i=0,k01r=0,k01i=0,k10r=0,k10i=0,k11r=0,k11i=0;
    for (int n = 0; n < 64; ++n) {
        double dr = gr - (double)Lr[n];
        double di = gi - (double)Li[n];
        double id2 = 1.0 / (dr*dr + di*di);
        double vr =  dr * id2;
        double vi = -di * id2;
        double a0r = (double)Cr[n], a0i = -(double)Ci[n];
        double a1r = (double)Pr[n], a1i = -(double)Pi[n];
        double br  = (double)Br[n], bi  = (double)Bi[n];
        double pr  = (double)Pr[n], pi  = (double)Pi[n];
        double e00r = a0r*br - a0i*bi, e00i = a0r*bi + a0i*br;
        double e01r = a0r*pr - a0i*pi, e01i = a0r*pi + a0i*pr;
        double e10r = a1r*br - a1i*bi, e10i = a1r*bi + a1i*br;
        double e11r = a1r*pr - a1i*pi, e11i = a1r*pi + a1i*pr;
        k00r += vr*e00r - vi*e00i;  k00i += vr*e00i + vi*e00r;
        k01r += vr*e01r - vi*e01i;  k01i += vr*e01i + vi*e01r;
        k10r += vr*e10r - vi*e10i;  k10i += vr*e10i + vi*e10r;
        k11r += vr*e11r - vi*e11i;  k11i += vr*e11i + vi*e11r;
    }
    double rr = 1.0 + k11r, ri = k11i;
    double ir2 = 1.0 / (rr*rr + ri*ri);
    double qr0 = k01r*k10r - k01i*k10i;
    double qi0 = k01r*k10i + k01i*k10r;
    double qr = (qr0*rr + qi0*ri) * ir2;
    double qi = (qi0*rr - qr0*ri) * ir2;
    double sr = k00r - qr, sim = k00i - qi;
    Kraw[m] = make_float2((float)(cr*sr - ci*sim), (float)(cr*sim + ci*sr));
}

// ---------------------------------------------------------------------------
// Kernel 2: build U,V tables for the real-input half-length convolution:
//   Ktilde[q] = (K[q] + conj(K[L-q]))/2          (Hermitian part -> real y)
//   alpha = Ktilde[k], beta = Ktilde[k+M]
//   P = (alpha+beta)/2, Q = (alpha-beta)/2, theta = 2*pi*k/L
//   U = (P - sin(theta)*Q)/M,  V = i*cos(theta)*Q/M
// so that  W[k] = U*Z[k] + V*conj(Z[(M-k)%M])  and  w = IDFT_M(W) gives
// y[2n] = Re w[n], y[2n+1] = Im w[n].
// Stored in the fft_conv (thread t, slot j) order:
//   k = (t>>5) + 16*((t>>1)&15) + 256*j + 4096*(t&1),  p = t*16 + j.
// ---------------------------------------------------------------------------
__global__ void s4_uv(const float2* __restrict__ Kraw, float4* __restrict__ UV)
{
    int p = blockIdx.x * blockDim.x + threadIdx.x;
    if (p >= MFFT) return;
    int t = p >> 4, j = p & 15;
    int k = (t >> 5) | (((t >> 1) & 15) << 4) | (j << 8) | ((t & 1) << 12);

    float2 Ka = Kraw[k];
    float2 Kb = Kraw[(LFFT - k) & (LFFT - 1)];
    float2 Kc = Kraw[k + MFFT];
    float2 Kd = Kraw[MFFT - k];   // = (L - (k+M)) mod L, valid for k=0 too
    double ar = 0.5 * ((double)Ka.x + (double)Kb.x);
    double ai = 0.5 * ((double)Ka.y - (double)Kb.y);
    double br = 0.5 * ((double)Kc.x + (double)Kd.x);
    double bi = 0.5 * ((double)Kc.y - (double)Kd.y);
    double Pr = 0.5 * (ar + br), Pi = 0.5 * (ai + bi);
    double Qr = 0.5 * (ar - br), Qi = 0.5 * (ai - bi);
    double th = (2.0 * M_PI / (double)LFFT) * (double)k;
    double sn, cs;
    sincos(th, &sn, &cs);
    double inv = 1.0 / (double)MFFT;
    double Ur = (Pr - sn * Qr) * inv, Ui = (Pi - sn * Qi) * inv;
    double Vr = (-cs * Qi) * inv,     Vi = ( cs * Qr) * inv;
    UV[p] = make_float4((float)Ur, (float)Ui, (float)Vr, (float)Vi);
}

// ---------------------------------------------------------------------------
// Kernel 3: one real row per block. z[n] = x[2n] + i*x[2n+1] (M=8192 complex),
// four-step FFT 8192 = 16 x 16 x 16 x 2 over 512 threads x 16 regs:
//   P1: DFT-16 over a (n = t + 512a), twiddle W_M^t          [T1 cross-wave]
//   P2: DFT-16 over b (tau = u + 32b), twiddle W_512^u       [T2 wave-local]
//   P3: DFT-16 over m (u = v + 2m),   twiddle W_32^v
//   DFT-2 over v via lane-pair shfl_xor(1)
// multiply W[k] = U*Z + V*conj(Z[-k]) (pair fetched via one LDS round-trip),
// then the mirrored inverse, ending in coalesced float2 stores.
// LDS = 512 rows x 17 float2 = 69,632 B -> 2 blocks/CU.
// ---------------------------------------------------------------------------
__global__ __launch_bounds__(NT, 4) void fft_conv(
    const float* __restrict__ x, float* __restrict__ y,
    const float2* __restrict__ twidM, const float4* __restrict__ UV)
{
    __shared__ float2 lds[NT * PITCH];
    const int t = threadIdx.x;
    const int u = t & 31;       // position-within-512 low digit
    const int g = t >> 5;       // k1 group
    const size_t base = (size_t)blockIdx.x * LFFT;
    const float2* xz = (const float2*)(x + base);

    float2 r[16];
    #pragma unroll
    for (int a = 0; a < 16; ++a) r[a] = xz[t + NT*a];

    // ---- P1: DFT-16 over a, twiddle W_8192^(t*k1) ----
    dft16_t<-1>(r);
    twiddle15(r, twidM[t]);

    // ---- T1 (cross-wave): r[k1] -> (row 32*k1 + u, col t>>5); read own row ----
    #pragma unroll
    for (int k = 0; k < 16; ++k)
        lds[(32*k + u) * PITCH + g] = r[k];
    __syncthreads();
    #pragma unroll
    for (int b = 0; b < 16; ++b) r[b] = lds[t * PITCH + b];
    LDS_FENCE();

    // ---- P2: DFT-16 over b, twiddle W_512^(u*k3) ----
    dft16_t<-1>(r);
    twiddle15(r, twidM[16 * u]);

    // ---- T2 (wave-local): r[k3] -> (row 32*k1 + 2*k3 + (u&1), col u>>1) ----
    #pragma unroll
    for (int k = 0; k < 16; ++k)
        lds[((t & ~31) + 2*k + (t & 1)) * PITCH + (u >> 1)] = r[k];
    LDS_FENCE();
    #pragma unroll
    for (int m = 0; m < 16; ++m) r[m] = lds[t * PITCH + m];
    LDS_FENCE();

    // ---- P3: DFT-16 over m, twiddle W_32^(v*k5), v = t&1 ----
    dft16_t<-1>(r);
    twiddle15(r, twidM[256 * (t & 1)]);

    // ---- DFT-2 over v: lane-pair exchange ----
    #pragma unroll
    for (int j = 0; j < 16; ++j) {
        float2 o;
        o.x = __shfl_xor(r[j].x, 1);
        o.y = __shfl_xor(r[j].y, 1);
        r[j] = (t & 1) ? csub(o, r[j]) : cadd(r[j], o);
    }
    // now r[j] = Z[k], k = g + 16*((t>>1)&15) + 256*j + 4096*(t&1)

    // ---- pairing: publish Z thread-major, fetch conj-partner, multiply ----
    #pragma unroll
    for (int j = 0; j < 16; ++j) lds[t * PITCH + j] = r[j];
    __syncthreads();
    {
        const float4* uv = UV + t * 16;
        const int kb = g | (((t >> 1) & 15) << 4) | ((t & 1) << 12);
        #pragma unroll
        for (int j = 0; j < 16; ++j) {
            int k  = kb + (j << 8);
            int kp = (MFFT - k) & (MFFT - 1);
            int tp = ((kp & 15) << 5) | (((kp >> 4) & 15) << 1) | (kp >> 12);
            int cp = (kp >> 8) & 15;
            float2 zp = lds[tp * PITCH + cp];
            float4 c  = uv[j];
            r[j] = cadd(cmul(make_float2(c.x, c.y), r[j]),
                        cmulc(make_float2(c.z, c.w), zp));
        }
    }
    __syncthreads();   // all pairing reads complete before IT2 overwrites

    // ---- inverse: IDFT-2 over k6 (same lane-pair combine) ----
    #pragma unroll
    for (int j = 0; j < 16; ++j) {
        float2 o;
        o.x = __shfl_xor(r[j].x, 1);
        o.y = __shfl_xor(r[j].y, 1);
        r[j] = (t & 1) ? csub(o, r[j]) : cadd(r[j], o);
    }
    // ---- IP3: conj twiddle W_32^v, inverse DFT-16 over k5 -> m ----
    { float2 w0 = twidM[256 * (t & 1)]; twiddle15(r, make_float2(w0.x, -w0.y)); }
    dft16_t<1>(r);

    // ---- IT2 (wave-local): r[m] -> (row 32*k1 + v + 2*m, col k3) ----
    #pragma unroll
    for (int m = 0; m < 16; ++m)
        lds[((t & ~31) + (t & 1) + 2*m) * PITCH + (u >> 1)] = r[m];
    LDS_FENCE();
    #pragma unroll
    for (int k = 0; k < 16; ++k) r[k] = lds[t * PITCH + k];

    // ---- IP2: conj twiddle W_512^u, inverse DFT-16 over k3 -> b ----
    { float2 w0 = twidM[16 * u]; twiddle15(r, make_float2(w0.x, -w0.y)); }
    dft16_t<1>(r);

    // ---- IT1 (cross-wave): r[b] -> (row u + 32*b, col k1) ----
    __syncthreads();
    #pragma unroll
    for (int b = 0; b < 16; ++b)
        lds[(u + 32*b) * PITCH + g] = r[b];
    __syncthreads();
    #pragma unroll
    for (int k = 0; k < 16; ++k) r[k] = lds[t * PITCH + k];

    // ---- IP1: conj twiddle W_8192^t, inverse DFT-16 over k1 -> a ----
    { float2 w0 = twidM[t]; twiddle15(r, make_float2(w0.x, -w0.y)); }
    dft16_t<1>(r);

    // ---- store: w[n] = (y[2n], y[2n+1]) coalesced ----
    float2* yz = (float2*)(y + base);
    #pragma unroll
    for (int a = 0; a < 16; ++a) yz[t + NT*a] = r[a];
}

extern "C" void kernel_launch(void* const* d_in, const int* in_sizes, int n_in,
                              void* d_out, int out_size, void* d_ws, size_t ws_size,
                              hipStream_t stream)
{
    const float* x  = (const float*)d_in[0];
    const float* Lr = (const float*)d_in[1];
    const float* Li = (const float*)d_in[2];
    const float* Pr = (const float*)d_in[3];
    const float* Pi = (const float*)d_in[4];
    const float* Br = (const float*)d_in[5];
    const float* Bi = (const float*)d_in[6];
    const float* Cr = (const float*)d_in[7];
    const float* Ci = (const float*)d_in[8];
    const float* st = (const float*)d_in[9];

    const int rows = in_sizes[0] / LFFT;   // 1024

    float2* Kraw  = (float2*)d_ws;          // LFFT float2  (128 KB)
    float2* twidM = Kraw + LFFT;            // MFFT float2  ( 64 KB)
    float4* UV    = (float4*)(twidM + MFFT);// MFFT float4  (128 KB)

    s4_eval<<<LFFT / 64, 64, 0, stream>>>(Lr, Li, Pr, Pi, Br, Bi, Cr, Ci, st,
                                          Kraw, twidM);
    s4_uv<<<MFFT / 64, 64, 0, stream>>>(Kraw, UV);
    fft_conv<<<rows, NT, 0, stream>>>(x, (float*)d_out, twidM, UV);
}